// Round 2
// baseline (22772.733 us; speedup 1.0000x reference)
//
#include <hip/hip_runtime.h>
#include <hip/hip_bf16.h>
#include <hip/hip_cooperative_groups.h>

namespace cg = cooperative_groups;

typedef __hip_bfloat16 bf16;
typedef short v8s __attribute__((ext_vector_type(8)));
typedef float v4f __attribute__((ext_vector_type(4)));
typedef float v16f __attribute__((ext_vector_type(16)));

static __device__ __forceinline__ float bf2f(bf16 x) { return __bfloat162float(x); }

// ---------------- zero h double-buffers + loss ----------------
__global__ __launch_bounds__(256) void k_zero(float* __restrict__ hzero, float* __restrict__ loss) {
    int idx = blockIdx.x * 256 + threadIdx.x;
    if (idx < 131072) hzero[idx] = 0.0f;      // h0buf[2] + h1buf[2], bf16 = 524288 B
    if (idx == 0) loss[0] = 0.0f;
}

// ---------------- recurrent weights -> bf16, K-concat [l][n][2048] ----------------
__global__ __launch_bounds__(256) void k_convert_w(const float* __restrict__ Wih,
                                                   const float* __restrict__ Whh,
                                                   bf16* __restrict__ Wb) {
    int idx = blockIdx.x * 256 + threadIdx.x;    // < 16,777,216
    int k2 = idx & 2047;
    int ln = idx >> 11;
    float v = (k2 < 1024) ? Wih[ln * 1024 + k2] : Whh[ln * 1024 + (k2 - 1024)];
    Wb[idx] = __float2bfloat16(v);
}

__global__ __launch_bounds__(256) void k_convert_small(const float* __restrict__ Wout,
                                                       const float* __restrict__ bih,
                                                       const float* __restrict__ bhh,
                                                       bf16* __restrict__ Wob,
                                                       float* __restrict__ bsum) {
    int idx = blockIdx.x * 256 + threadIdx.x;
    if (idx < 262144) Wob[idx] = __float2bfloat16(Wout[idx]);
    int bidx = idx - 262144;
    if (bidx >= 0 && bidx < 8192) bsum[bidx] = bih[bidx] + bhh[bidx];
}

// ---------------- embedding gather -> bf16, layout [t][b][k] ----------------
__global__ __launch_bounds__(256) void k_embed(const int* __restrict__ X,
                                               const float* __restrict__ embed,
                                               bf16* __restrict__ x0) {
    int bi = blockIdx.x;          // (t*64 + b)*4 + kc
    int kc = bi & 3;
    int tb = bi >> 2;
    int b  = tb & 63;
    int t  = tb >> 6;
    int k  = kc * 256 + threadIdx.x;
    int tok = X[b * 512 + t];
    x0[(long)tb * 1024 + k] = __float2bfloat16(embed[tok * 1024 + k]);
}

// ---------------- persistent cooperative LSTM: all 511 steps, both layers ----------------
// 256 WGs x 512 thr. WG g: layer = g>>7, j = g&127 owns h-cols 8j..8j+7 (32 gate rows).
// Wave w: M-half m = w&1 (batches 32m..), K-quarter q = w>>1 (k in q*512..+512).
// Weights: 32 x v8s per lane in VGPRs, loaded once. c-state lives in LDS.
__global__ __launch_bounds__(512, 2) void k_lstm(bf16* __restrict__ x0all,   // [511][64][1024]
                                                 bf16* __restrict__ x1buf,   // [2][64][1024]
                                                 bf16* __restrict__ h0buf,   // [2][64][1024]
                                                 bf16* __restrict__ h1buf,   // [2][64][1024]
                                                 const bf16* __restrict__ Wb,
                                                 const float* __restrict__ bsum) {
    __shared__ float g_part[8][32][33];   // [wave][batch-in-half][gate-col], padded
    __shared__ float c_lds[64][9];        // cell state, padded
    __shared__ float b_lds[32];

    const int g     = blockIdx.x;
    const int layer = g >> 7;
    const int j     = g & 127;
    const int tid   = threadIdx.x;
    const int l     = tid & 63;
    const int w     = tid >> 6;     // 0..7
    const int m     = w & 1;
    const int q     = w >> 1;       // 0..3
    const int nn    = l & 31;       // gate-col within tile: gt*8 + c
    const int kh    = l >> 5;       // k-half of K-step

    if (tid < 32) b_lds[tid] = bsum[layer * 4096 + (tid >> 3) * 1024 + (j << 3) + (tid & 7)];
    for (int i = tid; i < 576; i += 512) ((float*)c_lds)[i] = 0.f;

    // weights -> VGPRs (row = gt*1024 + 8j + c; k slice = q*512 + kk*16 + kh*8)
    const bf16* wbase = Wb + (long)layer * 8388608
                      + (long)((nn >> 3) * 1024 + (j << 3) + (nn & 7)) * 2048
                      + q * 512 + kh * 8;
    v8s wreg[32];
#pragma unroll
    for (int kk = 0; kk < 32; ++kk) wreg[kk] = *(const v8s*)(wbase + kk * 16);

    cg::grid_group grid = cg::this_grid();

    for (int s = 0; s < 512; ++s) {
        grid.sync();
        const bool act = (layer == 0) ? (s < 511) : (s >= 1);
        const bf16* xop;  const bf16* hop;  bf16* hdst;  bf16* resdst;  const bf16* ressrc;
        if (layer == 0) {
            xop    = x0all + (long)s * 65536;
            hop    = h0buf + ((s + 1) & 1) * 65536;
            hdst   = h0buf + (s & 1) * 65536;
            resdst = x1buf + (s & 1) * 65536;
            ressrc = xop;
        } else {
            xop    = x1buf + ((s + 1) & 1) * 65536;
            hop    = h1buf + ((s + 1) & 1) * 65536;
            hdst   = h1buf + (s & 1) * 65536;
            resdst = x0all + (long)(s - 1) * 65536;
            ressrc = xop;
        }
        if (act) {
            const bf16* Ab = ((q < 2) ? (xop + q * 512) : (hop + (q - 2) * 512))
                           + ((m << 5) + nn) * 1024 + kh * 8;
            v16f acc = {0.f,0.f,0.f,0.f,0.f,0.f,0.f,0.f,0.f,0.f,0.f,0.f,0.f,0.f,0.f,0.f};
#pragma unroll
            for (int kk = 0; kk < 32; ++kk) {
                v8s a = *(const v8s*)(Ab + kk * 16);
                acc = __builtin_amdgcn_mfma_f32_32x32x16_bf16(a, wreg[kk], acc, 0, 0, 0);
            }
#pragma unroll
            for (int r = 0; r < 16; ++r)   // D: col=lane&31, row=(r&3)+8*(r>>2)+4*(lane>>5)
                g_part[w][(r & 3) + ((r >> 2) << 3) + (kh << 2)][nn] = acc[r];
        }
        __syncthreads();
        if (act) {
            const int c  = tid >> 6;       // 0..7 (uniform per wave)
            const int b  = tid & 63;
            const int mm = b >> 5, br = b & 31;
            float gi = 0.f, gf = 0.f, gg = 0.f, go = 0.f;
#pragma unroll
            for (int qq = 0; qq < 4; ++qq) {
                gi += g_part[(qq << 1) | mm][br][c];
                gf += g_part[(qq << 1) | mm][br][8 + c];
                gg += g_part[(qq << 1) | mm][br][16 + c];
                go += g_part[(qq << 1) | mm][br][24 + c];
            }
            gi += b_lds[c]; gf += b_lds[8 + c]; gg += b_lds[16 + c]; go += b_lds[24 + c];
            const float si = 1.f / (1.f + __expf(-gi));
            const float sf = 1.f / (1.f + __expf(-gf));
            const float so = 1.f / (1.f + __expf(-go));
            const float tg = tanhf(gg);
            const float cn = sf * c_lds[b][c] + si * tg;
            c_lds[b][c] = cn;
            const float hn = so * tanhf(cn);
            const int off = b * 1024 + (j << 3) + c;
            hdst[off]   = __float2bfloat16(hn);
            resdst[off] = __float2bfloat16(hn + bf2f(ressrc[off]));
        }
    }
}

// ---------------- output projection + CE, one WG per timestep ----------------
__global__ __launch_bounds__(256) void k_final(const bf16* __restrict__ outAll,
                                               const bf16* __restrict__ Wob,
                                               const float* __restrict__ bout,
                                               const int* __restrict__ X,
                                               float* __restrict__ loss) {
    const int t    = blockIdx.x;
    const int tid  = threadIdx.x;
    const int lane = tid & 63;
    const int w    = tid >> 6;
    const int col  = lane & 15;
    const int oct  = lane >> 4;
    const bf16* arow = outAll + ((long)t * 64 + (w << 4) + col) * 1024 + (oct << 3);
    v4f acc[16];
#pragma unroll
    for (int nt = 0; nt < 16; ++nt) acc[nt] = (v4f){0.f, 0.f, 0.f, 0.f};
    for (int k0 = 0; k0 < 1024; k0 += 32) {
        v8s a = *(const v8s*)(arow + k0);
#pragma unroll
        for (int nt = 0; nt < 16; ++nt) {
            v8s bb = *(const v8s*)(Wob + ((nt << 4) + col) * 1024 + (oct << 3) + k0);
            acc[nt] = __builtin_amdgcn_mfma_f32_16x16x32_bf16(a, bb, acc[nt], 0, 0, 0);
        }
    }
#pragma unroll
    for (int nt = 0; nt < 16; ++nt) {
        const float bb = bout[(nt << 4) + col];
        acc[nt][0] += bb; acc[nt][1] += bb; acc[nt][2] += bb; acc[nt][3] += bb;
    }
    float ce_sum = 0.f;
#pragma unroll
    for (int r = 0; r < 4; ++r) {
        float mx = -3.4e38f;
#pragma unroll
        for (int nt = 0; nt < 16; ++nt) mx = fmaxf(mx, acc[nt][r]);
#pragma unroll
        for (int mm = 1; mm < 16; mm <<= 1) mx = fmaxf(mx, __shfl_xor(mx, mm, 64));
        float s = 0.f;
#pragma unroll
        for (int nt = 0; nt < 16; ++nt) s += __expf(acc[nt][r] - mx);
#pragma unroll
        for (int mm = 1; mm < 16; mm <<= 1) s += __shfl_xor(s, mm, 64);
        const int b   = (w << 4) + (oct << 2) + r;
        const int tok = X[b * 512 + t + 1];
        float lt = 0.f;
#pragma unroll
        for (int nt = 0; nt < 16; ++nt)
            if ((tok >> 4) == nt) lt = acc[nt][r];
        if ((tok & 15) == col)
            ce_sum += mx + __logf(s) - lt;
    }
#pragma unroll
    for (int mm = 1; mm < 64; mm <<= 1) ce_sum += __shfl_xor(ce_sum, mm, 64);
    if (lane == 0) atomicAdd(loss, ce_sum * (1.0f / 32768.0f));
}

extern "C" void kernel_launch(void* const* d_in, const int* in_sizes, int n_in,
                              void* d_out, int out_size, void* d_ws, size_t ws_size,
                              hipStream_t stream) {
    const int*   X     = (const int*)  d_in[0];
    const float* embed = (const float*)d_in[1];
    const float* Wih   = (const float*)d_in[2];
    const float* Whh   = (const float*)d_in[3];
    const float* bih   = (const float*)d_in[4];
    const float* bhh   = (const float*)d_in[5];
    const float* Wout  = (const float*)d_in[6];
    const float* bout  = (const float*)d_in[7];
    float* loss = (float*)d_out;

    // workspace layout (bytes), total = 101,875,712
    char* ws = (char*)d_ws;
    bf16*  x0all = (bf16*)(ws + 0);            // 511*64*1024 bf16
    bf16*  Wb    = (bf16*)(ws + 66977792);     // 2*4096*2048 bf16
    bf16*  Wob   = (bf16*)(ws + 100532224);    // 256*1024 bf16
    bf16*  x1buf = (bf16*)(ws + 101056512);    // 2*64*1024 bf16
    bf16*  h0buf = (bf16*)(ws + 101318656);    // 2*64*1024 bf16
    bf16*  h1buf = (bf16*)(ws + 101580800);    // 2*64*1024 bf16
    float* bsum  = (float*)(ws + 101842944);   // 2*4096 f32
    float* hzero = (float*)(ws + 101318656);   // h0buf+h1buf as f32 words

    if (ws_size < 101875712u) return;

    k_zero<<<512, 256, 0, stream>>>(hzero, loss);
    k_convert_w<<<65536, 256, 0, stream>>>(Wih, Whh, Wb);
    k_convert_small<<<1056, 256, 0, stream>>>(Wout, bih, bhh, Wob, bsum);
    k_embed<<<130816, 256, 0, stream>>>(X, embed, x0all);

    void* args[] = {&x0all, &x1buf, &h0buf, &h1buf, &Wb, &bsum};
    hipLaunchCooperativeKernel((void*)k_lstm, dim3(256), dim3(512), args, 0, stream);

    k_final<<<511, 256, 0, stream>>>(x0all, Wob, bout, X, loss);
}

// Round 3
// 11161.703 us; speedup vs baseline: 2.0403x; 2.0403x over previous
//
#include <hip/hip_runtime.h>
#include <hip/hip_bf16.h>

typedef __hip_bfloat16 bf16;
typedef short v8s __attribute__((ext_vector_type(8)));
typedef float v4f __attribute__((ext_vector_type(4)));
typedef float v16f __attribute__((ext_vector_type(16)));

static __device__ __forceinline__ float bf2f(bf16 x) { return __bfloat162float(x); }

// ---------------- zero state region (x1buf..barrier) + loss ----------------
__global__ __launch_bounds__(256) void k_zero(float* __restrict__ zbase, float* __restrict__ loss) {
    int idx = blockIdx.x * 256 + threadIdx.x;
    if (idx < 205824) zbase[idx] = 0.0f;   // x1buf,h0buf,h1buf,bsum-area? no: x1..h1 + bsum + barrier
    if (idx == 0) loss[0] = 0.0f;
}

// ---------------- recurrent weights -> bf16, K-concat [l][n][2048] ----------------
__global__ __launch_bounds__(256) void k_convert_w(const float* __restrict__ Wih,
                                                   const float* __restrict__ Whh,
                                                   bf16* __restrict__ Wb) {
    int idx = blockIdx.x * 256 + threadIdx.x;    // < 16,777,216
    int k2 = idx & 2047;
    int ln = idx >> 11;
    float v = (k2 < 1024) ? Wih[ln * 1024 + k2] : Whh[ln * 1024 + (k2 - 1024)];
    Wb[idx] = __float2bfloat16(v);
}

__global__ __launch_bounds__(256) void k_convert_small(const float* __restrict__ Wout,
                                                       const float* __restrict__ bih,
                                                       const float* __restrict__ bhh,
                                                       bf16* __restrict__ Wob,
                                                       float* __restrict__ bsum) {
    int idx = blockIdx.x * 256 + threadIdx.x;
    if (idx < 262144) Wob[idx] = __float2bfloat16(Wout[idx]);
    int bidx = idx - 262144;
    if (bidx >= 0 && bidx < 8192) bsum[bidx] = bih[bidx] + bhh[bidx];
}

// ---------------- embedding gather -> bf16, layout [t][b][k] ----------------
__global__ __launch_bounds__(256) void k_embed(const int* __restrict__ X,
                                               const float* __restrict__ embed,
                                               bf16* __restrict__ x0) {
    int bi = blockIdx.x;
    int kc = bi & 3;
    int tb = bi >> 2;
    int b  = tb & 63;
    int t  = tb >> 6;
    int k  = kc * 256 + threadIdx.x;
    int tok = X[b * 512 + t];
    x0[(long)tb * 1024 + k] = __float2bfloat16(embed[tok * 1024 + k]);
}

// ---------------- persistent LSTM with hand-rolled tree barrier ----------------
// 256 WGs x 512 thr. WG g: layer = g>>7, j = g&127 owns h-cols 8j..8j+7 (32 gate rows).
// Wave w: m = w&1 (M-half), q = w>>1 (K-quarter). Weights pinned in VGPRs via asm.
__global__ __launch_bounds__(512, 2) void k_lstm(bf16* __restrict__ x0all,
                                                 bf16* __restrict__ x1buf,
                                                 bf16* __restrict__ h0buf,
                                                 bf16* __restrict__ h1buf,
                                                 const bf16* __restrict__ Wb,
                                                 const float* __restrict__ bsum,
                                                 unsigned* bar) {
    __shared__ float g_part[8][32][33];
    __shared__ float c_lds[64][9];
    __shared__ float b_lds[32];

    const int g     = blockIdx.x;
    const int layer = g >> 7;
    const int j     = g & 127;
    const int tid   = threadIdx.x;
    const int l     = tid & 63;
    const int w     = tid >> 6;
    const int m     = w & 1;
    const int q     = w >> 1;
    const int nn    = l & 31;
    const int kh    = l >> 5;

    unsigned* leaf = bar + (g >> 4) * 32;   // 16 leaves, 128B apart
    unsigned* root = bar + 512;
    unsigned* gen  = bar + 544;

    if (tid < 32) b_lds[tid] = bsum[layer * 4096 + (tid >> 3) * 1024 + (j << 3) + (tid & 7)];
    for (int i = tid; i < 576; i += 512) ((float*)c_lds)[i] = 0.f;

    const bf16* wbase = Wb + (long)layer * 8388608
                      + (long)((nn >> 3) * 1024 + (j << 3) + (nn & 7)) * 2048
                      + q * 512 + kh * 8;
    v8s wreg[32];
#pragma unroll
    for (int kk = 0; kk < 32; ++kk) wreg[kk] = *(const v8s*)(wbase + kk * 16);
#pragma unroll
    for (int kk = 0; kk < 32; ++kk) asm volatile("" : "+v"(wreg[kk]));  // pin: no remat/reload

    const int bb_ = tid >> 3;        // activation: batch
    const int cc_ = tid & 7;         // activation: column within WG's 8
    const int mmb = bb_ >> 5, br = bb_ & 31;
    const bool pre = (layer == 0) && (q < 2);   // layer-0 x-part is barrier-independent

    for (int s = 0; s < 512; ++s) {
        const bool act = (layer == 0) ? (s < 511) : (s >= 1);
        const bf16* xop; const bf16* hop; bf16* hdst; bf16* resdst; const bf16* ressrc;
        if (layer == 0) {
            xop    = x0all + (long)s * 65536;
            hop    = h0buf + ((s + 1) & 1) * 65536;
            hdst   = h0buf + (s & 1) * 65536;
            resdst = x1buf + (s & 1) * 65536;
            ressrc = xop;
        } else {
            xop    = x1buf + ((s + 1) & 1) * 65536;
            hop    = h1buf + ((s + 1) & 1) * 65536;
            hdst   = h1buf + (s & 1) * 65536;
            resdst = x0all + (long)(s - 1) * 65536;
            ressrc = xop;
        }
        const bf16* Aq = ((q < 2) ? (xop + q * 512) : (hop + (q - 2) * 512))
                       + ((m << 5) + nn) * 1024 + kh * 8;
        v16f acc = {0.f,0.f,0.f,0.f,0.f,0.f,0.f,0.f,0.f,0.f,0.f,0.f,0.f,0.f,0.f,0.f};
        if (act && pre) {          // pre-barrier: x-part of layer 0 (x0all[s] is stable)
#pragma unroll
            for (int kk = 0; kk < 32; ++kk) {
                v8s a = *(const v8s*)(Aq + kk * 16);
                acc = __builtin_amdgcn_mfma_f32_32x32x16_bf16(a, wreg[kk], acc, 0, 0, 0);
            }
        }
        // ---- barrier WAIT (phase s): all WGs finished writing step s-1 ----
        if (tid == 0 && s > 0) {
            while (__hip_atomic_load(gen, __ATOMIC_RELAXED, __HIP_MEMORY_SCOPE_AGENT) < (unsigned)s)
                __builtin_amdgcn_s_sleep(1);
            __threadfence();       // acquire: invalidate stale L1/L2 lines
        }
        __syncthreads();
        if (act && !pre) {
#pragma unroll
            for (int kk = 0; kk < 32; ++kk) {
                v8s a = *(const v8s*)(Aq + kk * 16);
                acc = __builtin_amdgcn_mfma_f32_32x32x16_bf16(a, wreg[kk], acc, 0, 0, 0);
            }
        }
        if (act) {
#pragma unroll
            for (int r = 0; r < 16; ++r)   // D: col=lane&31, row=(r&3)+8*(r>>2)+4*(lane>>5)
                g_part[w][(r & 3) + ((r >> 2) << 3) + (kh << 2)][nn] = acc[r];
        }
        __syncthreads();
        if (act) {
            float gi = 0.f, gf = 0.f, gg = 0.f, go = 0.f;
#pragma unroll
            for (int qq = 0; qq < 4; ++qq) {
                gi += g_part[(qq << 1) | mmb][br][cc_];
                gf += g_part[(qq << 1) | mmb][br][8 + cc_];
                gg += g_part[(qq << 1) | mmb][br][16 + cc_];
                go += g_part[(qq << 1) | mmb][br][24 + cc_];
            }
            gi += b_lds[cc_]; gf += b_lds[8 + cc_]; gg += b_lds[16 + cc_]; go += b_lds[24 + cc_];
            const float si = 1.f / (1.f + __expf(-gi));
            const float sf = 1.f / (1.f + __expf(-gf));
            const float so = 1.f / (1.f + __expf(-go));
            const float tg = tanhf(gg);
            const float cn = sf * c_lds[bb_][cc_] + si * tg;
            c_lds[bb_][cc_] = cn;
            const float hn = so * tanhf(cn);
            const int off = bb_ * 1024 + (j << 3) + cc_;   // 8 lanes -> 16B coalesced chunk
            hdst[off]   = __float2bfloat16(hn);
            resdst[off] = __float2bfloat16(hn + bf2f(ressrc[off]));
        }
        // ---- barrier ARRIVE (publish phase s+1) ----
        __syncthreads();
        if (tid == 0) {
            __threadfence();       // release: push h/res writes toward LLC
            unsigned a = __hip_atomic_fetch_add(leaf, 1u, __ATOMIC_RELAXED, __HIP_MEMORY_SCOPE_AGENT) + 1;
            if (a == (unsigned)(s + 1) * 16u) {
                __threadfence();
                unsigned r = __hip_atomic_fetch_add(root, 1u, __ATOMIC_RELAXED, __HIP_MEMORY_SCOPE_AGENT) + 1;
                if (r == (unsigned)(s + 1) * 16u) {
                    __hip_atomic_store(gen, (unsigned)(s + 1), __ATOMIC_RELEASE, __HIP_MEMORY_SCOPE_AGENT);
                }
            }
        }
    }
}

// ---------------- output projection + CE, one WG per timestep ----------------
__global__ __launch_bounds__(256) void k_final(const bf16* __restrict__ outAll,
                                               const bf16* __restrict__ Wob,
                                               const float* __restrict__ bout,
                                               const int* __restrict__ X,
                                               float* __restrict__ loss) {
    const int t    = blockIdx.x;
    const int tid  = threadIdx.x;
    const int lane = tid & 63;
    const int w    = tid >> 6;
    const int col  = lane & 15;
    const int oct  = lane >> 4;
    const bf16* arow = outAll + ((long)t * 64 + (w << 4) + col) * 1024 + (oct << 3);
    v4f acc[16];
#pragma unroll
    for (int nt = 0; nt < 16; ++nt) acc[nt] = (v4f){0.f, 0.f, 0.f, 0.f};
    for (int k0 = 0; k0 < 1024; k0 += 32) {
        v8s a = *(const v8s*)(arow + k0);
#pragma unroll
        for (int nt = 0; nt < 16; ++nt) {
            v8s bb = *(const v8s*)(Wob + ((nt << 4) + col) * 1024 + (oct << 3) + k0);
            acc[nt] = __builtin_amdgcn_mfma_f32_16x16x32_bf16(a, bb, acc[nt], 0, 0, 0);
        }
    }
#pragma unroll
    for (int nt = 0; nt < 16; ++nt) {
        const float bb = bout[(nt << 4) + col];
        acc[nt][0] += bb; acc[nt][1] += bb; acc[nt][2] += bb; acc[nt][3] += bb;
    }
    float ce_sum = 0.f;
#pragma unroll
    for (int r = 0; r < 4; ++r) {
        float mx = -3.4e38f;
#pragma unroll
        for (int nt = 0; nt < 16; ++nt) mx = fmaxf(mx, acc[nt][r]);
#pragma unroll
        for (int mm = 1; mm < 16; mm <<= 1) mx = fmaxf(mx, __shfl_xor(mx, mm, 64));
        float s = 0.f;
#pragma unroll
        for (int nt = 0; nt < 16; ++nt) s += __expf(acc[nt][r] - mx);
#pragma unroll
        for (int mm = 1; mm < 16; mm <<= 1) s += __shfl_xor(s, mm, 64);
        const int b   = (w << 4) + (oct << 2) + r;
        const int tok = X[b * 512 + t + 1];
        float lt = 0.f;
#pragma unroll
        for (int nt = 0; nt < 16; ++nt)
            if ((tok >> 4) == nt) lt = acc[nt][r];
        if ((tok & 15) == col)
            ce_sum += mx + __logf(s) - lt;
    }
#pragma unroll
    for (int mm = 1; mm < 64; mm <<= 1) ce_sum += __shfl_xor(ce_sum, mm, 64);
    if (lane == 0) atomicAdd(loss, ce_sum * (1.0f / 32768.0f));
}

extern "C" void kernel_launch(void* const* d_in, const int* in_sizes, int n_in,
                              void* d_out, int out_size, void* d_ws, size_t ws_size,
                              hipStream_t stream) {
    const int*   X     = (const int*)  d_in[0];
    const float* embed = (const float*)d_in[1];
    const float* Wih   = (const float*)d_in[2];
    const float* Whh   = (const float*)d_in[3];
    const float* bih   = (const float*)d_in[4];
    const float* bhh   = (const float*)d_in[5];
    const float* Wout  = (const float*)d_in[6];
    const float* bout  = (const float*)d_in[7];
    float* loss = (float*)d_out;

    // workspace layout (bytes), total = 101,879,808
    char* ws = (char*)d_ws;
    bf16*     x0all = (bf16*)(ws + 0);            // 511*64*1024 bf16
    bf16*     Wb    = (bf16*)(ws + 66977792);     // 2*4096*2048 bf16
    bf16*     Wob   = (bf16*)(ws + 100532224);    // 256*1024 bf16
    bf16*     x1buf = (bf16*)(ws + 101056512);    // 2*64*1024 bf16
    bf16*     h0buf = (bf16*)(ws + 101318656);    // 2*64*1024 bf16
    bf16*     h1buf = (bf16*)(ws + 101580800);    // 2*64*1024 bf16
    float*    bsum  = (float*)(ws + 101842944);   // 2*4096 f32
    unsigned* bar   = (unsigned*)(ws + 101875712);// 4096 B barrier state
    float*    zbase = (float*)(ws + 101056512);   // zero x1..bar = 823,296 B = 205,824 words

    if (ws_size < 101879808u) return;

    k_zero<<<804, 256, 0, stream>>>(zbase, loss);
    k_convert_w<<<65536, 256, 0, stream>>>(Wih, Whh, Wb);
    k_convert_small<<<1056, 256, 0, stream>>>(Wout, bih, bhh, Wob, bsum);
    k_embed<<<130816, 256, 0, stream>>>(X, embed, x0all);

    void* args[] = {&x0all, &x1buf, &h0buf, &h1buf, &Wb, &bsum, &bar};
    hipLaunchCooperativeKernel((void*)k_lstm, dim3(256), dim3(512), args, 0, stream);

    k_final<<<511, 256, 0, stream>>>(x0all, Wob, bout, X, loss);
}

// Round 4
// 8346.771 us; speedup vs baseline: 2.7283x; 1.3372x over previous
//
#include <hip/hip_runtime.h>
#include <hip/hip_bf16.h>

typedef __hip_bfloat16 bf16;
typedef short v8s __attribute__((ext_vector_type(8)));
typedef float v4f __attribute__((ext_vector_type(4)));
typedef float v16f __attribute__((ext_vector_type(16)));
typedef unsigned long long u64;

static __device__ __forceinline__ float bf2f(bf16 x) { return __bfloat162float(x); }
static __device__ __forceinline__ unsigned short bfbits(float f) {
    bf16 t = __float2bfloat16(f);
    return *(unsigned short*)&t;
}

// ---------------- zero h buffers + barrier + loss ----------------
__global__ __launch_bounds__(256) void k_zero(float* __restrict__ zbase, float* __restrict__ loss) {
    int idx = blockIdx.x * 256 + threadIdx.x;
    if (idx < 140288) zbase[idx] = 0.0f;   // h0buf,h1buf,bsum(overwritten later),bar
    if (idx == 0) loss[0] = 0.0f;
}

// ---------------- recurrent weights -> bf16, K-concat [l][n][2048] ----------------
__global__ __launch_bounds__(256) void k_convert_w(const float* __restrict__ Wih,
                                                   const float* __restrict__ Whh,
                                                   bf16* __restrict__ Wb) {
    int idx = blockIdx.x * 256 + threadIdx.x;    // < 16,777,216
    int k2 = idx & 2047;
    int ln = idx >> 11;
    float v = (k2 < 1024) ? Wih[ln * 1024 + k2] : Whh[ln * 1024 + (k2 - 1024)];
    Wb[idx] = __float2bfloat16(v);
}

__global__ __launch_bounds__(256) void k_convert_small(const float* __restrict__ Wout,
                                                       const float* __restrict__ bih,
                                                       const float* __restrict__ bhh,
                                                       bf16* __restrict__ Wob,
                                                       float* __restrict__ bsum) {
    int idx = blockIdx.x * 256 + threadIdx.x;
    if (idx < 262144) Wob[idx] = __float2bfloat16(Wout[idx]);
    int bidx = idx - 262144;
    if (bidx >= 0 && bidx < 8192) bsum[bidx] = bih[bidx] + bhh[bidx];
}

// ---------------- embedding gather -> bf16, layout [t][b][k] ----------------
__global__ __launch_bounds__(256) void k_embed(const int* __restrict__ X,
                                               const float* __restrict__ embed,
                                               bf16* __restrict__ x0) {
    int bi = blockIdx.x;
    int kc = bi & 3;
    int tb = bi >> 2;
    int b  = tb & 63;
    int t  = tb >> 6;
    int k  = kc * 256 + threadIdx.x;
    int tok = X[b * 512 + t];
    x0[(long)tb * 1024 + k] = __float2bfloat16(embed[tok * 1024 + k]);
}

// ===== asm helpers =====
#define GLD_C(dst, p)  asm volatile("global_load_dwordx4 %0, %1, off"         : "=v"(dst) : "v"(p))
#define GLD_B(dst, p)  asm volatile("global_load_dwordx4 %0, %1, off sc0 sc1" : "=v"(dst) : "v"(p))
#define MFMA(acc, a, w) asm volatile("v_mfma_f32_32x32x16_bf16 %0, %1, %2, %0" : "+v"(acc) : "v"(a), "a"(w))
#define VW8() asm volatile("s_waitcnt vmcnt(8)")
#define VW0() asm volatile("s_waitcnt vmcnt(0)")
#define ZACC(a) do { _Pragma("unroll") for (int r_ = 0; r_ < 16; ++r_) a[r_] = 0.f; } while(0)

#define ISSUE(GLD, c, B) do { _Pragma("unroll") for (int i_ = 0; i_ < 4; ++i_) { \
    GLD(B[2*i_],   pA0 + (c)*64 + i_*16); \
    GLD(B[2*i_+1], pA1 + (c)*64 + i_*16); } } while(0)

#define CHUNK(c, B) do { _Pragma("unroll") for (int i_ = 0; i_ < 4; ++i_) { \
    MFMA(acc00, B[2*i_],   wa0[(c)*4+i_]); \
    MFMA(acc10, B[2*i_+1], wa0[(c)*4+i_]); \
    MFMA(acc01, B[2*i_],   wa1[(c)*4+i_]); \
    MFMA(acc11, B[2*i_+1], wa1[(c)*4+i_]); } } while(0)

#define PIPE(GLD) do { \
    ISSUE(GLD,0,bufa); ISSUE(GLD,1,bufb); \
    VW8(); CHUNK(0,bufa); ISSUE(GLD,2,bufa); \
    VW8(); CHUNK(1,bufb); ISSUE(GLD,3,bufb); \
    VW8(); CHUNK(2,bufa); ISSUE(GLD,4,bufa); \
    VW8(); CHUNK(3,bufb); ISSUE(GLD,5,bufb); \
    VW8(); CHUNK(4,bufa); ISSUE(GLD,6,bufa); \
    VW8(); CHUNK(5,bufb); ISSUE(GLD,7,bufb); \
    VW8(); CHUNK(6,bufa); \
    VW0(); CHUNK(7,bufb); } while(0)

#define WRGP(OP) do { _Pragma("unroll") for (int r_ = 0; r_ < 16; ++r_) { \
    const int grow_ = (r_&3) + ((r_>>2)<<3) + ((l>>5)<<2); \
    gp[q&1][grow_][l&31]          OP acc00[r_]; \
    gp[q&1][grow_][32+(l&31)]     OP acc01[r_]; \
    gp[q&1][32+grow_][l&31]       OP acc10[r_]; \
    gp[q&1][32+grow_][32+(l&31)]  OP acc11[r_]; } } while(0)

// ---------------- persistent LSTM: 128 WGs x 256 thr, no-fence sc-coherent barrier ----------------
// WG g: layer = g>>6, j = g&63 owns h-dims 16j..16j+15 (64 gate rows, N=64).
// Wave q (0..3): K-slice q*512..+512 (q<2 = x-part, q>=2 = h-part), both M-halves.
// Weights: 64 x v8s per lane pinned in AGPRs (256 AGPR), MFMA reads them directly.
__global__ __launch_bounds__(256, 1) void k_lstm(bf16* __restrict__ x0all,
                                                 bf16* __restrict__ x1buf,
                                                 bf16* __restrict__ h0buf,
                                                 bf16* __restrict__ h1buf,
                                                 const bf16* __restrict__ Wb,
                                                 const float* __restrict__ bsum,
                                                 unsigned* bar) {
    __shared__ float gp[2][64][67];   // 2 reduce slots (waves 2,3 RMW into 0,1)
    __shared__ float c_lds[64][17];
    __shared__ float b_lds[64];

    const int g     = blockIdx.x;    // 0..127
    const int layer = g >> 6;
    const int j     = g & 63;
    const int tid   = threadIdx.x;
    const int l     = tid & 63;
    const int q     = tid >> 6;      // 0..3

    unsigned* leaf = bar + (g >> 4) * 32;   // 8 leaves, 128B apart
    unsigned* root = bar + 512;
    unsigned* gen  = bar + 544;

    if (tid < 64) b_lds[tid] = bsum[layer * 4096 + (tid >> 4) * 1024 + (j << 4) + (tid & 15)];
    for (int i = tid; i < 64 * 17; i += 256) ((float*)c_lds)[i] = 0.f;

    // ---- weights -> AGPRs (pinned) ----
    // row n_local = ni*32 + (l&31): gate = n_local>>4, dim = n_local&15
    const int nl0 = l & 31, nl1 = 32 + (l & 31);
    const long N0 = (long)((nl0 >> 4) * 1024 + (j << 4) + (nl0 & 15));
    const long N1 = (long)((nl1 >> 4) * 1024 + (j << 4) + (nl1 & 15));
    const bf16* wp0 = Wb + (long)layer * 8388608 + N0 * 2048 + q * 512 + ((l >> 5) << 3);
    const bf16* wp1 = Wb + (long)layer * 8388608 + N1 * 2048 + q * 512 + ((l >> 5) << 3);
    v8s wa0[32], wa1[32];
#pragma unroll
    for (int kk = 0; kk < 32; ++kk) {
        wa0[kk] = *(const v8s*)(wp0 + kk * 16);
        asm volatile("" : "+a"(wa0[kk]));
        wa1[kk] = *(const v8s*)(wp1 + kk * 16);
        asm volatile("" : "+a"(wa1[kk]));
    }

    const int ab = tid >> 2;        // activation: batch 0..63
    const int dq = tid & 3;         // activation: dim quad
    const bool prewave = (layer == 0) && (q < 2);

#pragma unroll 1
    for (int s = 0; s < 512; ++s) {
        const bool act = (layer == 0) ? (s < 511) : (s >= 1);
        const bf16* xop = x0all + (long)s * 65536;
        const bf16* x1p = x1buf + ((s + 1) & 1) * 65536;
        const bf16* h0p = h0buf + ((s + 1) & 1) * 65536;
        const bf16* h1p = h1buf + ((s + 1) & 1) * 65536;
        bf16* hdst  = (layer ? h1buf : h0buf) + (s & 1) * 65536;
        bf16* x1dst = x1buf + (s & 1) * 65536;
        bf16* res1  = x0all + (long)(s - 1) * 65536;

        const bf16* base = (layer == 0) ? ((q < 2) ? xop : h0p)
                                        : ((q < 2) ? x1p : h1p);
        const bf16* pA0 = base + ((q & 1) << 9) + (l & 31) * 1024 + ((l >> 5) << 3);
        const bf16* pA1 = pA0 + 32 * 1024;

        v16f acc00, acc01, acc10, acc11;
        v8s bufa[8], bufb[8];

        if (act && prewave) {           // layer-0 x-part: cached loads, runs under barrier wait
            ZACC(acc00); ZACC(acc01); ZACC(acc10); ZACC(acc11);
            PIPE(GLD_C);
            WRGP(=);
        }
        if (tid == 0 && s > 0) {
            while (__hip_atomic_load(gen, __ATOMIC_RELAXED, __HIP_MEMORY_SCOPE_AGENT) < (unsigned)s)
                __builtin_amdgcn_s_sleep(1);
        }
        __syncthreads();                // A: step s-1 globally complete
        if (act && !prewave) {          // mutable panels: LLC-bypass loads
            ZACC(acc00); ZACC(acc01); ZACC(acc10); ZACC(acc11);
            PIPE(GLD_B);
            if (q < 2) WRGP(=);         // layer-1 waves 0,1
        }
        __syncthreads();                // B1: slots 0,1 written
        if (act && q >= 2) WRGP(+=);    // waves 2,3 reduce into slots 0,1
        __syncthreads();                // B2: partials complete

        if (act) {
            // residual source (4 bf16)
            u64 xv;
            if (layer == 0) {
                xv = *(const u64*)(xop + ab * 1024 + (j << 4) + dq * 4);
            } else {
                const bf16* xrp = x1p + ab * 1024 + (j << 4) + dq * 4;
                asm volatile("global_load_dwordx2 %0, %1, off sc0 sc1" : "=v"(xv) : "v"(xrp));
            }
            float hv4[4], rv4[4];
#pragma unroll
            for (int i = 0; i < 4; ++i) {
                const int d = dq * 4 + i;
                const float gi = gp[0][ab][d]      + gp[1][ab][d]      + b_lds[d];
                const float gf = gp[0][ab][16 + d] + gp[1][ab][16 + d] + b_lds[16 + d];
                const float gg = gp[0][ab][32 + d] + gp[1][ab][32 + d] + b_lds[32 + d];
                const float go = gp[0][ab][48 + d] + gp[1][ab][48 + d] + b_lds[48 + d];
                const float si = 1.f / (1.f + __expf(-gi));
                const float sf = 1.f / (1.f + __expf(-gf));
                const float so = 1.f / (1.f + __expf(-go));
                const float tg = tanhf(gg);
                const float cn = sf * c_lds[ab][d] + si * tg;
                c_lds[ab][d] = cn;
                hv4[i] = so * tanhf(cn);
            }
            if (layer != 0) VW0();      // xv (asm load) ready
#pragma unroll
            for (int i = 0; i < 4; ++i) {
                const unsigned us = (unsigned)((xv >> (16 * i)) & 0xffffu);
                rv4[i] = hv4[i] + __uint_as_float(us << 16);
            }
            u64 hv64 = 0, rv64 = 0;
#pragma unroll
            for (int i = 0; i < 4; ++i) {
                hv64 |= (u64)bfbits(hv4[i]) << (16 * i);
                rv64 |= (u64)bfbits(rv4[i]) << (16 * i);
            }
            const int off = ab * 1024 + (j << 4) + dq * 4;
            bf16* hp = hdst + off;
            asm volatile("global_store_dwordx2 %0, %1, off sc0 sc1" :: "v"(hp), "v"(hv64) : "memory");
            if (layer == 0) {
                bf16* rp = x1dst + off;
                asm volatile("global_store_dwordx2 %0, %1, off sc0 sc1" :: "v"(rp), "v"(rv64) : "memory");
            } else {
                *(u64*)(res1 + off) = rv64;   // read only by k_final (post-flush)
            }
        }
        VW0();                          // all my stores at LLC
        __syncthreads();                // C
        if (tid == 0) {
            unsigned a = __hip_atomic_fetch_add(leaf, 1u, __ATOMIC_RELAXED, __HIP_MEMORY_SCOPE_AGENT) + 1;
            if (a == (unsigned)(s + 1) * 16u) {
                unsigned r = __hip_atomic_fetch_add(root, 1u, __ATOMIC_RELAXED, __HIP_MEMORY_SCOPE_AGENT) + 1;
                if (r == (unsigned)(s + 1) * 8u)
                    __hip_atomic_store(gen, (unsigned)(s + 1), __ATOMIC_RELAXED, __HIP_MEMORY_SCOPE_AGENT);
            }
        }
    }
}

// ---------------- output projection + CE, one WG per timestep ----------------
__global__ __launch_bounds__(256) void k_final(const bf16* __restrict__ outAll,
                                               const bf16* __restrict__ Wob,
                                               const float* __restrict__ bout,
                                               const int* __restrict__ X,
                                               float* __restrict__ loss) {
    const int t    = blockIdx.x;
    const int tid  = threadIdx.x;
    const int lane = tid & 63;
    const int w    = tid >> 6;
    const int col  = lane & 15;
    const int oct  = lane >> 4;
    const bf16* arow = outAll + ((long)t * 64 + (w << 4) + col) * 1024 + (oct << 3);
    v4f acc[16];
#pragma unroll
    for (int nt = 0; nt < 16; ++nt) acc[nt] = (v4f){0.f, 0.f, 0.f, 0.f};
    for (int k0 = 0; k0 < 1024; k0 += 32) {
        v8s a = *(const v8s*)(arow + k0);
#pragma unroll
        for (int nt = 0; nt < 16; ++nt) {
            v8s bb = *(const v8s*)(Wob + ((nt << 4) + col) * 1024 + (oct << 3) + k0);
            acc[nt] = __builtin_amdgcn_mfma_f32_16x16x32_bf16(a, bb, acc[nt], 0, 0, 0);
        }
    }
#pragma unroll
    for (int nt = 0; nt < 16; ++nt) {
        const float bb = bout[(nt << 4) + col];
        acc[nt][0] += bb; acc[nt][1] += bb; acc[nt][2] += bb; acc[nt][3] += bb;
    }
    float ce_sum = 0.f;
#pragma unroll
    for (int r = 0; r < 4; ++r) {
        float mx = -3.4e38f;
#pragma unroll
        for (int nt = 0; nt < 16; ++nt) mx = fmaxf(mx, acc[nt][r]);
#pragma unroll
        for (int mm = 1; mm < 16; mm <<= 1) mx = fmaxf(mx, __shfl_xor(mx, mm, 64));
        float ss = 0.f;
#pragma unroll
        for (int nt = 0; nt < 16; ++nt) ss += __expf(acc[nt][r] - mx);
#pragma unroll
        for (int mm = 1; mm < 16; mm <<= 1) ss += __shfl_xor(ss, mm, 64);
        const int b   = (w << 4) + (oct << 2) + r;
        const int tok = X[b * 512 + t + 1];
        float lt = 0.f;
#pragma unroll
        for (int nt = 0; nt < 16; ++nt)
            if ((tok >> 4) == nt) lt = acc[nt][r];
        if ((tok & 15) == col)
            ce_sum += mx + __logf(ss) - lt;
    }
#pragma unroll
    for (int mm = 1; mm < 64; mm <<= 1) ce_sum += __shfl_xor(ce_sum, mm, 64);
    if (lane == 0) atomicAdd(loss, ce_sum * (1.0f / 32768.0f));
}

extern "C" void kernel_launch(void* const* d_in, const int* in_sizes, int n_in,
                              void* d_out, int out_size, void* d_ws, size_t ws_size,
                              hipStream_t stream) {
    const int*   X     = (const int*)  d_in[0];
    const float* embed = (const float*)d_in[1];
    const float* Wih   = (const float*)d_in[2];
    const float* Whh   = (const float*)d_in[3];
    const float* bih   = (const float*)d_in[4];
    const float* bhh   = (const float*)d_in[5];
    const float* Wout  = (const float*)d_in[6];
    const float* bout  = (const float*)d_in[7];
    float* loss = (float*)d_out;

    // workspace layout (bytes), total = 101,879,808
    char* ws = (char*)d_ws;
    bf16*     x0all = (bf16*)(ws + 0);            // 511*64*1024 bf16
    bf16*     Wb    = (bf16*)(ws + 66977792);     // 2*4096*2048 bf16
    bf16*     Wob   = (bf16*)(ws + 100532224);    // 256*1024 bf16
    bf16*     x1buf = (bf16*)(ws + 101056512);    // 2*64*1024 bf16
    bf16*     h0buf = (bf16*)(ws + 101318656);    // 2*64*1024 bf16
    bf16*     h1buf = (bf16*)(ws + 101580800);    // 2*64*1024 bf16
    float*    bsum  = (float*)(ws + 101842944);   // 2*4096 f32
    unsigned* bar   = (unsigned*)(ws + 101875712);// 4096 B barrier state
    float*    zbase = (float*)(ws + 101318656);   // zero h0..bar = 561,152 B = 140,288 words

    if (ws_size < 101879808u) return;

    k_zero<<<548, 256, 0, stream>>>(zbase, loss);
    k_convert_w<<<65536, 256, 0, stream>>>(Wih, Whh, Wb);
    k_convert_small<<<1056, 256, 0, stream>>>(Wout, bih, bhh, Wob, bsum);
    k_embed<<<130816, 256, 0, stream>>>(X, embed, x0all);

    void* args[] = {&x0all, &x1buf, &h0buf, &h1buf, &Wb, &bsum, &bar};
    hipLaunchCooperativeKernel((void*)k_lstm, dim3(128), dim3(256), args, 0, stream);

    k_final<<<511, 256, 0, stream>>>(x0all, Wob, bout, X, loss);
}

// Round 5
// 6821.747 us; speedup vs baseline: 3.3383x; 1.2236x over previous
//
#include <hip/hip_runtime.h>
#include <hip/hip_bf16.h>

typedef __hip_bfloat16 bf16;
typedef short v8s __attribute__((ext_vector_type(8)));
typedef float v4f __attribute__((ext_vector_type(4)));
typedef float v16f __attribute__((ext_vector_type(16)));
typedef unsigned long long u64;

static __device__ __forceinline__ float bf2f(bf16 x) { return __bfloat162float(x); }
static __device__ __forceinline__ unsigned short bfbits(float f) {
    bf16 t = __float2bfloat16(f);
    return *(unsigned short*)&t;
}
static __device__ __forceinline__ float fast_tanh(float x) {
    float e = __expf(-2.f * x);
    return (1.f - e) / (1.f + e);
}

// ---------------- zero h buffers + barrier + loss ----------------
__global__ __launch_bounds__(256) void k_zero(float* __restrict__ zbase, float* __restrict__ loss) {
    int idx = blockIdx.x * 256 + threadIdx.x;
    if (idx < 140288) zbase[idx] = 0.0f;   // h0buf,h1buf,bsum,bar
    if (idx == 0) loss[0] = 0.0f;
}

// ---------------- recurrent weights -> bf16, K-concat [l][n][2048] ----------------
__global__ __launch_bounds__(256) void k_convert_w(const float* __restrict__ Wih,
                                                   const float* __restrict__ Whh,
                                                   bf16* __restrict__ Wb) {
    int idx = blockIdx.x * 256 + threadIdx.x;    // < 16,777,216
    int k2 = idx & 2047;
    int ln = idx >> 11;
    float v = (k2 < 1024) ? Wih[ln * 1024 + k2] : Whh[ln * 1024 + (k2 - 1024)];
    Wb[idx] = __float2bfloat16(v);
}

__global__ __launch_bounds__(256) void k_convert_small(const float* __restrict__ Wout,
                                                       const float* __restrict__ bih,
                                                       const float* __restrict__ bhh,
                                                       bf16* __restrict__ Wob,
                                                       float* __restrict__ bsum) {
    int idx = blockIdx.x * 256 + threadIdx.x;
    if (idx < 262144) Wob[idx] = __float2bfloat16(Wout[idx]);
    int bidx = idx - 262144;
    if (bidx >= 0 && bidx < 8192) bsum[bidx] = bih[bidx] + bhh[bidx];
}

// ---------------- embedding gather -> bf16, layout [t][b][k] ----------------
__global__ __launch_bounds__(256) void k_embed(const int* __restrict__ X,
                                               const float* __restrict__ embed,
                                               bf16* __restrict__ x0) {
    int bi = blockIdx.x;
    int kc = bi & 3;
    int tb = bi >> 2;
    int b  = tb & 63;
    int t  = tb >> 6;
    int k  = kc * 256 + threadIdx.x;
    int tok = X[b * 512 + t];
    x0[(long)tb * 1024 + k] = __float2bfloat16(embed[tok * 1024 + k]);
}

// ===== asm helpers =====
#define GLDI_C(dst, p, o) asm volatile("global_load_dwordx4 %0, %1, off offset:%2"         : "=v"(dst) : "v"(p), "i"(o))
#define GLDI_B(dst, p, o) asm volatile("global_load_dwordx4 %0, %1, off offset:%2 sc0 sc1" : "=v"(dst) : "v"(p), "i"(o))
#define MFMA(acc, a, w) asm volatile("v_mfma_f32_32x32x16_bf16 %0, %1, %2, %0" : "+v"(acc) : "v"(a), "a"(w))
#define VW(n)  asm volatile("s_waitcnt vmcnt(%0)" :: "i"(n))
#define VW0()  asm volatile("s_waitcnt vmcnt(0)")
#define ZACC(a) do { _Pragma("unroll") for (int r_ = 0; r_ < 16; ++r_) a[r_] = 0.f; } while(0)

// chunk c: 64 K-cols = 128 bytes; lane covers 16B at i*32
#define ISSUE(GLD, c, B) do { \
    GLD(B[0], pA0, (c)*128 +  0); GLD(B[1], pA1, (c)*128 +  0); \
    GLD(B[2], pA0, (c)*128 + 32); GLD(B[3], pA1, (c)*128 + 32); \
    GLD(B[4], pA0, (c)*128 + 64); GLD(B[5], pA1, (c)*128 + 64); \
    GLD(B[6], pA0, (c)*128 + 96); GLD(B[7], pA1, (c)*128 + 96); } while(0)

#define CHUNK(c, B) do { _Pragma("unroll") for (int i_ = 0; i_ < 4; ++i_) { \
    MFMA(acc00, B[2*i_],   wa0[(c)*4+i_]); \
    MFMA(acc10, B[2*i_+1], wa0[(c)*4+i_]); \
    MFMA(acc01, B[2*i_],   wa1[(c)*4+i_]); \
    MFMA(acc11, B[2*i_+1], wa1[(c)*4+i_]); } } while(0)

// 32 outstanding dwordx4 per wave (deep LLC pipeline)
#define PIPE(GLD) do { \
    ISSUE(GLD,0,bufa); ISSUE(GLD,1,bufb); ISSUE(GLD,2,bufc); ISSUE(GLD,3,bufd); \
    VW(24); CHUNK(0,bufa); ISSUE(GLD,4,bufa); \
    VW(24); CHUNK(1,bufb); ISSUE(GLD,5,bufb); \
    VW(24); CHUNK(2,bufc); ISSUE(GLD,6,bufc); \
    VW(24); CHUNK(3,bufd); ISSUE(GLD,7,bufd); \
    VW(24); CHUNK(4,bufa); \
    VW(16); CHUNK(5,bufb); \
    VW(8);  CHUNK(6,bufc); \
    VW(0);  CHUNK(7,bufd); } while(0)

#define WRGP(OP) do { _Pragma("unroll") for (int r_ = 0; r_ < 16; ++r_) { \
    const int grow_ = (r_&3) + ((r_>>2)<<3) + ((l>>5)<<2); \
    gp[q&1][grow_][l&31]          OP acc00[r_]; \
    gp[q&1][grow_][32+(l&31)]     OP acc01[r_]; \
    gp[q&1][32+grow_][l&31]       OP acc10[r_]; \
    gp[q&1][32+grow_][32+(l&31)]  OP acc11[r_]; } } while(0)

// ---------------- persistent LSTM: 128 WGs x 256 thr, flat-counter barrier ----------------
// WG g: layer = g>>6, j = g&63 owns h-dims 16j..16j+15 (64 gate rows, N=64).
// Wave q (0..3): K-slice q*512..+512 (q<2 = x-part, q>=2 = h-part), both M-halves.
// Weights: 64 x v8s per lane pinned in AGPRs (256 AGPR), MFMA reads them directly.
__global__ __launch_bounds__(256, 1) void k_lstm(bf16* __restrict__ x0all,
                                                 bf16* __restrict__ x1buf,
                                                 bf16* __restrict__ h0buf,
                                                 bf16* __restrict__ h1buf,
                                                 const bf16* __restrict__ Wb,
                                                 const float* __restrict__ bsum,
                                                 unsigned* bar) {
    __shared__ float gp[2][64][67];
    __shared__ float c_lds[64][17];
    __shared__ float b_lds[64];

    const int g     = blockIdx.x;    // 0..127
    const int layer = g >> 6;
    const int j     = g & 63;
    const int tid   = threadIdx.x;
    const int l     = tid & 63;
    const int q     = tid >> 6;      // 0..3

    unsigned* cnt = bar;             // single flat arrival counter, phase-encoded

    if (tid < 64) b_lds[tid] = bsum[layer * 4096 + (tid >> 4) * 1024 + (j << 4) + (tid & 15)];
    for (int i = tid; i < 64 * 17; i += 256) ((float*)c_lds)[i] = 0.f;

    // ---- weights -> AGPRs (pinned) ----
    const int nl0 = l & 31, nl1 = 32 + (l & 31);
    const long N0 = (long)((nl0 >> 4) * 1024 + (j << 4) + (nl0 & 15));
    const long N1 = (long)((nl1 >> 4) * 1024 + (j << 4) + (nl1 & 15));
    const bf16* wp0 = Wb + (long)layer * 8388608 + N0 * 2048 + q * 512 + ((l >> 5) << 3);
    const bf16* wp1 = Wb + (long)layer * 8388608 + N1 * 2048 + q * 512 + ((l >> 5) << 3);
    v8s wa0[32], wa1[32];
#pragma unroll
    for (int kk = 0; kk < 32; ++kk) {
        wa0[kk] = *(const v8s*)(wp0 + kk * 16);
        asm volatile("" : "+a"(wa0[kk]));
        wa1[kk] = *(const v8s*)(wp1 + kk * 16);
        asm volatile("" : "+a"(wa1[kk]));
    }

    const int ab = tid >> 2;        // activation: batch 0..63
    const int dq = tid & 3;         // activation: dim quad
    const bool prewave = (layer == 0) && (q < 2);

#pragma unroll 1
    for (int s = 0; s < 512; ++s) {
        const bool act = (layer == 0) ? (s < 511) : (s >= 1);
        const bf16* xop = x0all + (long)s * 65536;
        const bf16* x1p = x1buf + ((s + 1) & 1) * 65536;
        const bf16* h0p = h0buf + ((s + 1) & 1) * 65536;
        const bf16* h1p = h1buf + ((s + 1) & 1) * 65536;
        bf16* hdst  = (layer ? h1buf : h0buf) + (s & 1) * 65536;
        bf16* x1dst = x1buf + (s & 1) * 65536;
        bf16* res1  = x0all + (long)(s - 1) * 65536;

        const bf16* base = (layer == 0) ? ((q < 2) ? xop : h0p)
                                        : ((q < 2) ? x1p : h1p);
        const bf16* pA0 = base + ((q & 1) << 9) + (l & 31) * 1024 + ((l >> 5) << 3);
        const bf16* pA1 = pA0 + 32 * 1024;

        v16f acc00, acc01, acc10, acc11;
        v8s bufa[8], bufb[8], bufc[8], bufd[8];

        if (act && prewave) {           // layer-0 x-part: cached loads, pre-gate
            ZACC(acc00); ZACC(acc01); ZACC(acc10); ZACC(acc11);
            PIPE(GLDI_C);
            WRGP(=);
        }
        // ---- flat gate: all WGs completed step s-1 ----
        if (tid == 0 && s > 0) {
            const unsigned tgt = 128u * (unsigned)s;
            while (__hip_atomic_load(cnt, __ATOMIC_RELAXED, __HIP_MEMORY_SCOPE_AGENT) < tgt) {}
        }
        __syncthreads();                // A
        if (act && !prewave) {          // mutable panels: LLC-bypass loads
            ZACC(acc00); ZACC(acc01); ZACC(acc10); ZACC(acc11);
            PIPE(GLDI_B);
            if (q < 2) WRGP(=);
        }
        __syncthreads();                // B1
        if (act && q >= 2) WRGP(+=);
        __syncthreads();                // B2

        if (act) {
            u64 xv;
            if (layer == 0) {
                xv = *(const u64*)(xop + ab * 1024 + (j << 4) + dq * 4);
            } else {
                const bf16* xrp = x1p + ab * 1024 + (j << 4) + dq * 4;
                asm volatile("global_load_dwordx2 %0, %1, off sc0 sc1" : "=v"(xv) : "v"(xrp));
            }
            float hv4[4];
#pragma unroll
            for (int i = 0; i < 4; ++i) {
                const int d = dq * 4 + i;
                const float gi = gp[0][ab][d]      + gp[1][ab][d]      + b_lds[d];
                const float gf = gp[0][ab][16 + d] + gp[1][ab][16 + d] + b_lds[16 + d];
                const float gg = gp[0][ab][32 + d] + gp[1][ab][32 + d] + b_lds[32 + d];
                const float go = gp[0][ab][48 + d] + gp[1][ab][48 + d] + b_lds[48 + d];
                const float si = 1.f / (1.f + __expf(-gi));
                const float sf = 1.f / (1.f + __expf(-gf));
                const float so = 1.f / (1.f + __expf(-go));
                const float tg = fast_tanh(gg);
                const float cn = sf * c_lds[ab][d] + si * tg;
                c_lds[ab][d] = cn;
                hv4[i] = so * fast_tanh(cn);
            }
            if (layer != 0) VW0();      // xv ready
            u64 hv64 = 0, rv64 = 0;
#pragma unroll
            for (int i = 0; i < 4; ++i) {
                const unsigned us = (unsigned)((xv >> (16 * i)) & 0xffffu);
                const float rv = hv4[i] + __uint_as_float(us << 16);
                hv64 |= (u64)bfbits(hv4[i]) << (16 * i);
                rv64 |= (u64)bfbits(rv) << (16 * i);
            }
            const int off = ab * 1024 + (j << 4) + dq * 4;
            bf16* hp = hdst + off;
            asm volatile("global_store_dwordx2 %0, %1, off sc0 sc1" :: "v"(hp), "v"(hv64) : "memory");
            if (layer == 0) {
                bf16* rp = x1dst + off;
                asm volatile("global_store_dwordx2 %0, %1, off sc0 sc1" :: "v"(rp), "v"(rv64) : "memory");
            } else {
                *(u64*)(res1 + off) = rv64;   // read only by k_final (post-flush)
            }
        }
        VW0();                          // my stores visible at LLC
        __syncthreads();                // C
        if (tid == 0)
            __hip_atomic_fetch_add(cnt, 1u, __ATOMIC_RELAXED, __HIP_MEMORY_SCOPE_AGENT);
    }
}

// ---------------- output projection + CE, one WG per timestep ----------------
__global__ __launch_bounds__(256) void k_final(const bf16* __restrict__ outAll,
                                               const bf16* __restrict__ Wob,
                                               const float* __restrict__ bout,
                                               const int* __restrict__ X,
                                               float* __restrict__ loss) {
    const int t    = blockIdx.x;
    const int tid  = threadIdx.x;
    const int lane = tid & 63;
    const int w    = tid >> 6;
    const int col  = lane & 15;
    const int oct  = lane >> 4;
    const bf16* arow = outAll + ((long)t * 64 + (w << 4) + col) * 1024 + (oct << 3);
    v4f acc[16];
#pragma unroll
    for (int nt = 0; nt < 16; ++nt) acc[nt] = (v4f){0.f, 0.f, 0.f, 0.f};
    for (int k0 = 0; k0 < 1024; k0 += 32) {
        v8s a = *(const v8s*)(arow + k0);
#pragma unroll
        for (int nt = 0; nt < 16; ++nt) {
            v8s bb = *(const v8s*)(Wob + ((nt << 4) + col) * 1024 + (oct << 3) + k0);
            acc[nt] = __builtin_amdgcn_mfma_f32_16x16x32_bf16(a, bb, acc[nt], 0, 0, 0);
        }
    }
#pragma unroll
    for (int nt = 0; nt < 16; ++nt) {
        const float bb = bout[(nt << 4) + col];
        acc[nt][0] += bb; acc[nt][1] += bb; acc[nt][2] += bb; acc[nt][3] += bb;
    }
    float ce_sum = 0.f;
#pragma unroll
    for (int r = 0; r < 4; ++r) {
        float mx = -3.4e38f;
#pragma unroll
        for (int nt = 0; nt < 16; ++nt) mx = fmaxf(mx, acc[nt][r]);
#pragma unroll
        for (int mm = 1; mm < 16; mm <<= 1) mx = fmaxf(mx, __shfl_xor(mx, mm, 64));
        float ss = 0.f;
#pragma unroll
        for (int nt = 0; nt < 16; ++nt) ss += __expf(acc[nt][r] - mx);
#pragma unroll
        for (int mm = 1; mm < 16; mm <<= 1) ss += __shfl_xor(ss, mm, 64);
        const int b   = (w << 4) + (oct << 2) + r;
        const int tok = X[b * 512 + t + 1];
        float lt = 0.f;
#pragma unroll
        for (int nt = 0; nt < 16; ++nt)
            if ((tok >> 4) == nt) lt = acc[nt][r];
        if ((tok & 15) == col)
            ce_sum += mx + __logf(ss) - lt;
    }
#pragma unroll
    for (int mm = 1; mm < 64; mm <<= 1) ce_sum += __shfl_xor(ce_sum, mm, 64);
    if (lane == 0) atomicAdd(loss, ce_sum * (1.0f / 32768.0f));
}

extern "C" void kernel_launch(void* const* d_in, const int* in_sizes, int n_in,
                              void* d_out, int out_size, void* d_ws, size_t ws_size,
                              hipStream_t stream) {
    const int*   X     = (const int*)  d_in[0];
    const float* embed = (const float*)d_in[1];
    const float* Wih   = (const float*)d_in[2];
    const float* Whh   = (const float*)d_in[3];
    const float* bih   = (const float*)d_in[4];
    const float* bhh   = (const float*)d_in[5];
    const float* Wout  = (const float*)d_in[6];
    const float* bout  = (const float*)d_in[7];
    float* loss = (float*)d_out;

    // workspace layout (bytes), total = 101,879,808
    char* ws = (char*)d_ws;
    bf16*     x0all = (bf16*)(ws + 0);            // 511*64*1024 bf16
    bf16*     Wb    = (bf16*)(ws + 66977792);     // 2*4096*2048 bf16
    bf16*     Wob   = (bf16*)(ws + 100532224);    // 256*1024 bf16
    bf16*     x1buf = (bf16*)(ws + 101056512);    // 2*64*1024 bf16
    bf16*     h0buf = (bf16*)(ws + 101318656);    // 2*64*1024 bf16
    bf16*     h1buf = (bf16*)(ws + 101580800);    // 2*64*1024 bf16
    float*    bsum  = (float*)(ws + 101842944);   // 2*4096 f32
    unsigned* bar   = (unsigned*)(ws + 101875712);// 4096 B barrier state
    float*    zbase = (float*)(ws + 101318656);   // zero h0..bar = 561,152 B

    if (ws_size < 101879808u) return;

    k_zero<<<548, 256, 0, stream>>>(zbase, loss);
    k_convert_w<<<65536, 256, 0, stream>>>(Wih, Whh, Wb);
    k_convert_small<<<1056, 256, 0, stream>>>(Wout, bih, bhh, Wob, bsum);
    k_embed<<<130816, 256, 0, stream>>>(X, embed, x0all);

    void* args[] = {&x0all, &x1buf, &h0buf, &h1buf, &Wb, &bsum, &bar};
    hipLaunchCooperativeKernel((void*)k_lstm, dim3(128), dim3(256), args, 0, stream);

    k_final<<<511, 256, 0, stream>>>(x0all, Wob, bout, X, loss);
}

// Round 6
// 6742.220 us; speedup vs baseline: 3.3776x; 1.0118x over previous
//
#include <hip/hip_runtime.h>
#include <hip/hip_bf16.h>

typedef __hip_bfloat16 bf16;
typedef short v8s __attribute__((ext_vector_type(8)));
typedef float v4f __attribute__((ext_vector_type(4)));
typedef float v16f __attribute__((ext_vector_type(16)));
typedef unsigned long long u64;

static __device__ __forceinline__ float bf2f(bf16 x) { return __bfloat162float(x); }
static __device__ __forceinline__ unsigned short bfbits(float f) {
    bf16 t = __float2bfloat16(f);
    return *(unsigned short*)&t;
}
static __device__ __forceinline__ float fast_tanh(float x) {
    float e = __expf(-2.f * x);
    return (1.f - e) / (1.f + e);
}

// ---------------- zero h buffers + barrier + loss ----------------
__global__ __launch_bounds__(256) void k_zero(float* __restrict__ zbase, float* __restrict__ loss) {
    int idx = blockIdx.x * 256 + threadIdx.x;
    if (idx < 140288) zbase[idx] = 0.0f;   // h0buf,h1buf,bsum,bar
    if (idx == 0) loss[0] = 0.0f;
}

// ---------------- recurrent weights -> bf16, K-concat [l][n][2048] ----------------
__global__ __launch_bounds__(256) void k_convert_w(const float* __restrict__ Wih,
                                                   const float* __restrict__ Whh,
                                                   bf16* __restrict__ Wb) {
    int idx = blockIdx.x * 256 + threadIdx.x;    // < 16,777,216
    int k2 = idx & 2047;
    int ln = idx >> 11;
    float v = (k2 < 1024) ? Wih[ln * 1024 + k2] : Whh[ln * 1024 + (k2 - 1024)];
    Wb[idx] = __float2bfloat16(v);
}

__global__ __launch_bounds__(256) void k_convert_small(const float* __restrict__ Wout,
                                                       const float* __restrict__ bih,
                                                       const float* __restrict__ bhh,
                                                       bf16* __restrict__ Wob,
                                                       float* __restrict__ bsum) {
    int idx = blockIdx.x * 256 + threadIdx.x;
    if (idx < 262144) Wob[idx] = __float2bfloat16(Wout[idx]);
    int bidx = idx - 262144;
    if (bidx >= 0 && bidx < 8192) bsum[bidx] = bih[bidx] + bhh[bidx];
}

// ---------------- embedding gather -> bf16, layout [t][b][k] ----------------
__global__ __launch_bounds__(256) void k_embed(const int* __restrict__ X,
                                               const float* __restrict__ embed,
                                               bf16* __restrict__ x0) {
    int bi = blockIdx.x;
    int kc = bi & 3;
    int tb = bi >> 2;
    int b  = tb & 63;
    int t  = tb >> 6;
    int k  = kc * 256 + threadIdx.x;
    int tok = X[b * 512 + t];
    x0[(long)tb * 1024 + k] = __float2bfloat16(embed[tok * 1024 + k]);
}

// ===== asm helpers =====
#define GLDI(dst, p, o) asm volatile("global_load_dwordx4 %0, %1, off offset:%2" : "=v"(dst) : "v"(p), "i"(o))
#define MFMA(acc, a, w) asm volatile("v_mfma_f32_32x32x16_bf16 %0, %1, %2, %0" : "+v"(acc) : "v"(a), "a"(w))
#define VW(n)  asm volatile("s_waitcnt vmcnt(%0)" :: "i"(n))
#define VW0()  asm volatile("s_waitcnt vmcnt(0)")
#define ZACC(a) do { _Pragma("unroll") for (int r_ = 0; r_ < 16; ++r_) a[r_] = 0.f; } while(0)

// chunk c: 64 K-cols = 128 bytes; lane covers 16B at i*32
#define ISSUE(c, B) do { \
    GLDI(B[0], pA0, (c)*128 +  0); GLDI(B[1], pA1, (c)*128 +  0); \
    GLDI(B[2], pA0, (c)*128 + 32); GLDI(B[3], pA1, (c)*128 + 32); \
    GLDI(B[4], pA0, (c)*128 + 64); GLDI(B[5], pA1, (c)*128 + 64); \
    GLDI(B[6], pA0, (c)*128 + 96); GLDI(B[7], pA1, (c)*128 + 96); } while(0)

#define CHUNK(c, B) do { _Pragma("unroll") for (int i_ = 0; i_ < 4; ++i_) { \
    MFMA(acc00, B[2*i_],   wa0[(c)*4+i_]); \
    MFMA(acc10, B[2*i_+1], wa0[(c)*4+i_]); \
    MFMA(acc01, B[2*i_],   wa1[(c)*4+i_]); \
    MFMA(acc11, B[2*i_+1], wa1[(c)*4+i_]); } } while(0)

// 32 outstanding dwordx4 per wave
#define PIPE() do { \
    ISSUE(0,bufa); ISSUE(1,bufb); ISSUE(2,bufc); ISSUE(3,bufd); \
    VW(24); CHUNK(0,bufa); ISSUE(4,bufa); \
    VW(24); CHUNK(1,bufb); ISSUE(5,bufb); \
    VW(24); CHUNK(2,bufc); ISSUE(6,bufc); \
    VW(24); CHUNK(3,bufd); ISSUE(7,bufd); \
    VW(24); CHUNK(4,bufa); \
    VW(16); CHUNK(5,bufb); \
    VW(8);  CHUNK(6,bufc); \
    VW(0);  CHUNK(7,bufd); } while(0)

#define WRGP(OP) do { _Pragma("unroll") for (int r_ = 0; r_ < 16; ++r_) { \
    const int grow_ = (r_&3) + ((r_>>2)<<3) + ((l>>5)<<2); \
    gp[q&1][grow_][l&31]          OP acc00[r_]; \
    gp[q&1][grow_][32+(l&31)]     OP acc01[r_]; \
    gp[q&1][32+grow_][l&31]       OP acc10[r_]; \
    gp[q&1][32+grow_][32+(l&31)]  OP acc11[r_]; } } while(0)

// ---------------- persistent LSTM: 128 WGs x 256 thr ----------------
// WG g: layer = g>>6, j = g&63 owns h-dims 16j..16j+15 (64 gate rows, N=64).
// Wave q (0..3): K-slice q*512..+512 (q<2 = x-part, q>=2 = h-part), both M-halves.
// Weights pinned in AGPRs. Panel loads L2-cached; coherence via per-phase
// agent-acquire fence (buffer_inv) after the gate; all mutable stores write-through.
// Barrier: 16 cache lines (8 WGs/line), per-layer gating, min-over-lines poll.
__global__ __launch_bounds__(256, 1) void k_lstm(bf16* __restrict__ x0all,
                                                 bf16* __restrict__ x1buf,
                                                 bf16* __restrict__ h0buf,
                                                 bf16* __restrict__ h1buf,
                                                 const bf16* __restrict__ Wb,
                                                 const float* __restrict__ bsum,
                                                 unsigned* bar) {
    __shared__ float gp[2][64][67];
    __shared__ float c_lds[64][17];
    __shared__ float b_lds[64];

    const int g     = blockIdx.x;    // 0..127
    const int layer = g >> 6;
    const int j     = g & 63;
    const int tid   = threadIdx.x;
    const int l     = tid & 63;
    const int q     = tid >> 6;      // 0..3

    unsigned* myline = bar + ((layer << 3) + (j & 7)) * 32;  // 16 lines, 128B apart

    if (tid < 64) b_lds[tid] = bsum[layer * 4096 + (tid >> 4) * 1024 + (j << 4) + (tid & 15)];
    for (int i = tid; i < 64 * 17; i += 256) ((float*)c_lds)[i] = 0.f;

    // ---- weights -> AGPRs (pinned) ----
    const int nl0 = l & 31, nl1 = 32 + (l & 31);
    const long N0 = (long)((nl0 >> 4) * 1024 + (j << 4) + (nl0 & 15));
    const long N1 = (long)((nl1 >> 4) * 1024 + (j << 4) + (nl1 & 15));
    const bf16* wp0 = Wb + (long)layer * 8388608 + N0 * 2048 + q * 512 + ((l >> 5) << 3);
    const bf16* wp1 = Wb + (long)layer * 8388608 + N1 * 2048 + q * 512 + ((l >> 5) << 3);
    v8s wa0[32], wa1[32];
#pragma unroll
    for (int kk = 0; kk < 32; ++kk) {
        wa0[kk] = *(const v8s*)(wp0 + kk * 16);
        asm volatile("" : "+a"(wa0[kk]));
        wa1[kk] = *(const v8s*)(wp1 + kk * 16);
        asm volatile("" : "+a"(wa1[kk]));
    }

    const int ab = tid >> 2;        // activation: batch 0..63
    const int dq = tid & 3;         // activation: dim quad
    const bool prewave = (layer == 0) && (q < 2);
    const int nlines = (layer == 0) ? 8 : 16;   // L0 gates on L0 only; L1 on both

#pragma unroll 1
    for (int s = 0; s < 512; ++s) {
        const bool act = (layer == 0) ? (s < 511) : (s >= 1);
        const bf16* xop = x0all + (long)s * 65536;
        const bf16* x1p = x1buf + ((s + 1) & 1) * 65536;
        const bf16* h0p = h0buf + ((s + 1) & 1) * 65536;
        const bf16* h1p = h1buf + ((s + 1) & 1) * 65536;
        bf16* hdst  = (layer ? h1buf : h0buf) + (s & 1) * 65536;
        bf16* x1dst = x1buf + (s & 1) * 65536;
        bf16* res1  = x0all + (long)(s - 1) * 65536;

        const bf16* base = (layer == 0) ? ((q < 2) ? xop : h0p)
                                        : ((q < 2) ? x1p : h1p);
        const bf16* pA0 = base + ((q & 1) << 9) + (l & 31) * 1024 + ((l >> 5) << 3);
        const bf16* pA1 = pA0 + 32 * 1024;

        v16f acc00, acc01, acc10, acc11;
        v8s bufa[8], bufb[8], bufc[8], bufd[8];

        if (act && prewave) {           // layer-0 x-part: immutable panel, pre-gate
            ZACC(acc00); ZACC(acc01); ZACC(acc10); ZACC(acc11);
            PIPE();
            WRGP(=);
        }
        // ---- gate: required producers completed phase s-1 ----
        if (tid == 0 && s > 0) {
            const unsigned tgt = 8u * (unsigned)s;
            for (;;) {
                unsigned mn = ~0u;
#pragma unroll
                for (int i = 0; i < 16; ++i) {
                    if (i < nlines) {
                        unsigned v = __hip_atomic_load(bar + i * 32, __ATOMIC_RELAXED, __HIP_MEMORY_SCOPE_AGENT);
                        mn = (v < mn) ? v : mn;
                    }
                }
                if (mn >= tgt) break;
                __builtin_amdgcn_s_sleep(1);
            }
            __builtin_amdgcn_fence(__ATOMIC_ACQUIRE, "agent");  // inv stale L1/L2 lines
        }
        __syncthreads();                // A
        if (act && !prewave) {          // mutable panels: L2-cached post-inv
            ZACC(acc00); ZACC(acc01); ZACC(acc10); ZACC(acc11);
            PIPE();
            if (q < 2) WRGP(=);
        }
        __syncthreads();                // B1
        if (act && q >= 2) WRGP(+=);
        __syncthreads();                // B2

        if (act) {
            const int off = ab * 1024 + (j << 4) + dq * 4;
            const u64 xv = (layer == 0) ? *(const u64*)(xop + off)
                                        : *(const u64*)(x1p + off);   // L2-hit (panel just read)
            float hv4[4];
#pragma unroll
            for (int i = 0; i < 4; ++i) {
                const int d = dq * 4 + i;
                const float gi = gp[0][ab][d]      + gp[1][ab][d]      + b_lds[d];
                const float gf = gp[0][ab][16 + d] + gp[1][ab][16 + d] + b_lds[16 + d];
                const float gg = gp[0][ab][32 + d] + gp[1][ab][32 + d] + b_lds[32 + d];
                const float go = gp[0][ab][48 + d] + gp[1][ab][48 + d] + b_lds[48 + d];
                const float si = 1.f / (1.f + __expf(-gi));
                const float sf = 1.f / (1.f + __expf(-gf));
                const float so = 1.f / (1.f + __expf(-go));
                const float tg = fast_tanh(gg);
                const float cn = sf * c_lds[ab][d] + si * tg;
                c_lds[ab][d] = cn;
                hv4[i] = so * fast_tanh(cn);
            }
            u64 hv64 = 0, rv64 = 0;
#pragma unroll
            for (int i = 0; i < 4; ++i) {
                const unsigned us = (unsigned)((xv >> (16 * i)) & 0xffffu);
                const float rv = hv4[i] + __uint_as_float(us << 16);
                hv64 |= (u64)bfbits(hv4[i]) << (16 * i);
                rv64 |= (u64)bfbits(rv) << (16 * i);
            }
            bf16* hp = hdst + off;
            asm volatile("global_store_dwordx2 %0, %1, off sc0 sc1" :: "v"(hp), "v"(hv64) : "memory");
            bf16* rp = (layer == 0) ? (x1dst + off) : (res1 + off);
            asm volatile("global_store_dwordx2 %0, %1, off sc0 sc1" :: "v"(rp), "v"(rv64) : "memory");
        }
        VW0();                          // my write-through stores at LLC
        __syncthreads();                // C
        if (tid == 0)
            __hip_atomic_fetch_add(myline, 1u, __ATOMIC_RELAXED, __HIP_MEMORY_SCOPE_AGENT);
    }
}

// ---------------- output projection + CE, one WG per timestep ----------------
__global__ __launch_bounds__(256) void k_final(const bf16* __restrict__ outAll,
                                               const bf16* __restrict__ Wob,
                                               const float* __restrict__ bout,
                                               const int* __restrict__ X,
                                               float* __restrict__ loss) {
    const int t    = blockIdx.x;
    const int tid  = threadIdx.x;
    const int lane = tid & 63;
    const int w    = tid >> 6;
    const int col  = lane & 15;
    const int oct  = lane >> 4;
    const bf16* arow = outAll + ((long)t * 64 + (w << 4) + col) * 1024 + (oct << 3);
    v4f acc[16];
#pragma unroll
    for (int nt = 0; nt < 16; ++nt) acc[nt] = (v4f){0.f, 0.f, 0.f, 0.f};
    for (int k0 = 0; k0 < 1024; k0 += 32) {
        v8s a = *(const v8s*)(arow + k0);
#pragma unroll
        for (int nt = 0; nt < 16; ++nt) {
            v8s bb = *(const v8s*)(Wob + ((nt << 4) + col) * 1024 + (oct << 3) + k0);
            acc[nt] = __builtin_amdgcn_mfma_f32_16x16x32_bf16(a, bb, acc[nt], 0, 0, 0);
        }
    }
#pragma unroll
    for (int nt = 0; nt < 16; ++nt) {
        const float bb = bout[(nt << 4) + col];
        acc[nt][0] += bb; acc[nt][1] += bb; acc[nt][2] += bb; acc[nt][3] += bb;
    }
    float ce_sum = 0.f;
#pragma unroll
    for (int r = 0; r < 4; ++r) {
        float mx = -3.4e38f;
#pragma unroll
        for (int nt = 0; nt < 16; ++nt) mx = fmaxf(mx, acc[nt][r]);
#pragma unroll
        for (int mm = 1; mm < 16; mm <<= 1) mx = fmaxf(mx, __shfl_xor(mx, mm, 64));
        float ss = 0.f;
#pragma unroll
        for (int nt = 0; nt < 16; ++nt) ss += __expf(acc[nt][r] - mx);
#pragma unroll
        for (int mm = 1; mm < 16; mm <<= 1) ss += __shfl_xor(ss, mm, 64);
        const int b   = (w << 4) + (oct << 2) + r;
        const int tok = X[b * 512 + t + 1];
        float lt = 0.f;
#pragma unroll
        for (int nt = 0; nt < 16; ++nt)
            if ((tok >> 4) == nt) lt = acc[nt][r];
        if ((tok & 15) == col)
            ce_sum += mx + __logf(ss) - lt;
    }
#pragma unroll
    for (int mm = 1; mm < 64; mm <<= 1) ce_sum += __shfl_xor(ce_sum, mm, 64);
    if (lane == 0) atomicAdd(loss, ce_sum * (1.0f / 32768.0f));
}

extern "C" void kernel_launch(void* const* d_in, const int* in_sizes, int n_in,
                              void* d_out, int out_size, void* d_ws, size_t ws_size,
                              hipStream_t stream) {
    const int*   X     = (const int*)  d_in[0];
    const float* embed = (const float*)d_in[1];
    const float* Wih   = (const float*)d_in[2];
    const float* Whh   = (const float*)d_in[3];
    const float* bih   = (const float*)d_in[4];
    const float* bhh   = (const float*)d_in[5];
    const float* Wout  = (const float*)d_in[6];
    const float* bout  = (const float*)d_in[7];
    float* loss = (float*)d_out;

    // workspace layout (bytes), total = 101,879,808
    char* ws = (char*)d_ws;
    bf16*     x0all = (bf16*)(ws + 0);            // 511*64*1024 bf16
    bf16*     Wb    = (bf16*)(ws + 66977792);     // 2*4096*2048 bf16
    bf16*     Wob   = (bf16*)(ws + 100532224);    // 256*1024 bf16
    bf16*     x1buf = (bf16*)(ws + 101056512);    // 2*64*1024 bf16
    bf16*     h0buf = (bf16*)(ws + 101318656);    // 2*64*1024 bf16
    bf16*     h1buf = (bf16*)(ws + 101580800);    // 2*64*1024 bf16
    float*    bsum  = (float*)(ws + 101842944);   // 2*4096 f32
    unsigned* bar   = (unsigned*)(ws + 101875712);// 4096 B barrier state (16 lines)
    float*    zbase = (float*)(ws + 101318656);   // zero h0..bar = 561,152 B

    if (ws_size < 101879808u) return;

    k_zero<<<548, 256, 0, stream>>>(zbase, loss);
    k_convert_w<<<65536, 256, 0, stream>>>(Wih, Whh, Wb);
    k_convert_small<<<1056, 256, 0, stream>>>(Wout, bih, bhh, Wob, bsum);
    k_embed<<<130816, 256, 0, stream>>>(X, embed, x0all);

    void* args[] = {&x0all, &x1buf, &h0buf, &h1buf, &Wb, &bsum, &bar};
    hipLaunchCooperativeKernel((void*)k_lstm, dim3(128), dim3(256), args, 0, stream);

    k_final<<<511, 256, 0, stream>>>(x0all, Wob, bout, X, loss);
}